// Round 1
// baseline (1386.732 us; speedup 1.0000x reference)
//
#include <hip/hip_runtime.h>

#define N_NODES 100000
#define N_EDGES 600000
#define H 128
#define G_NUM 64
#define LN_EPS 1e-5f

// LDS h-buffer row stride: 132 keeps float4 alignment for every row and
// gives <=2-way bank aliasing on the k-loop reads (4*132=528 -> bank step 16).
#define HS 132

// ---------------------------------------------------------------------------
// Kernel 1: edge scatter-add.  agg (== d_out) must be pre-zeroed.
// thread = (edge, 16B chunk): 32 chunks cover H=128 floats.
// ---------------------------------------------------------------------------
__global__ __launch_bounds__(256) void scatter_add_kernel(
    const float* __restrict__ node, const int* __restrict__ ei,
    float* __restrict__ agg)
{
    int tid = blockIdx.x * 256 + threadIdx.x;     // E*32 = 19.2M threads exactly
    int e  = tid >> 5;
    int ch = tid & 31;
    if (e >= N_EDGES) return;
    int src = ei[e];
    int dst = ei[N_EDGES + e];
    float4 v = ((const float4*)(node + (size_t)src * H))[ch];
    float* a = agg + (size_t)dst * H + ch * 4;
    unsafeAtomicAdd(a + 0, v.x);   // hw global_atomic_add_f32 (no CAS loop)
    unsafeAtomicAdd(a + 1, v.y);
    unsafeAtomicAdd(a + 2, v.z);
    unsafeAtomicAdd(a + 3, v.w);
}

// ---------------------------------------------------------------------------
// Fused 3-layer MLP helpers
// ---------------------------------------------------------------------------
__device__ __forceinline__ void stageW(float* __restrict__ Ws,
                                       const float* __restrict__ W, int tid)
{
#pragma unroll
    for (int j = 0; j < 16; ++j) {
        int idx4 = tid + j * 256;                 // 4096 float4 = 128x128
        ((float4*)Ws)[idx4] = ((const float4*)W)[idx4];
    }
}

// GEMM tile: out[r][c] = sum_k in[r][k]*Ws[k][c] + bias[c]
// thread (cc=tid&15, rr=tid>>4) owns cols {4cc..4cc+3, 64+4cc..} x rows {4rr..4rr+3}
__device__ __forceinline__ void gemm_tile(const float* __restrict__ inb,
                                          float* __restrict__ outb,
                                          const float* __restrict__ Ws,
                                          const float* __restrict__ bias, int tid)
{
    const int cc = tid & 15;
    const int rr = tid >> 4;
    const int c0 = 4 * cc, c1 = 64 + 4 * cc;
    float acc[4][8];
#pragma unroll
    for (int i = 0; i < 4; ++i)
#pragma unroll
        for (int j = 0; j < 8; ++j) acc[i][j] = 0.f;

    const float* in0 = inb + (4 * rr + 0) * HS;
    const float* in1 = inb + (4 * rr + 1) * HS;
    const float* in2 = inb + (4 * rr + 2) * HS;
    const float* in3 = inb + (4 * rr + 3) * HS;

    for (int k = 0; k < 128; k += 4) {
        float4 a0 = *(const float4*)(in0 + k);
        float4 a1 = *(const float4*)(in1 + k);
        float4 a2 = *(const float4*)(in2 + k);
        float4 a3 = *(const float4*)(in3 + k);
        float ar[4][4] = {{a0.x, a0.y, a0.z, a0.w},
                          {a1.x, a1.y, a1.z, a1.w},
                          {a2.x, a2.y, a2.z, a2.w},
                          {a3.x, a3.y, a3.z, a3.w}};
#pragma unroll
        for (int kk = 0; kk < 4; ++kk) {
            float4 w0 = *(const float4*)&Ws[(k + kk) * 128 + c0];
            float4 w1 = *(const float4*)&Ws[(k + kk) * 128 + c1];
            float wv[8] = {w0.x, w0.y, w0.z, w0.w, w1.x, w1.y, w1.z, w1.w};
#pragma unroll
            for (int i = 0; i < 4; ++i) {
                float av = ar[i][kk];
#pragma unroll
                for (int j = 0; j < 8; ++j)
                    acc[i][j] = fmaf(av, wv[j], acc[i][j]);
            }
        }
    }
    float4 bb0 = *(const float4*)&bias[c0];
    float4 bb1 = *(const float4*)&bias[c1];
#pragma unroll
    for (int i = 0; i < 4; ++i) {
        int r = 4 * rr + i;
        float4 o0 = make_float4(acc[i][0] + bb0.x, acc[i][1] + bb0.y,
                                acc[i][2] + bb0.z, acc[i][3] + bb0.w);
        float4 o1 = make_float4(acc[i][4] + bb1.x, acc[i][5] + bb1.y,
                                acc[i][6] + bb1.z, acc[i][7] + bb1.w);
        *(float4*)&outb[r * HS + c0] = o0;
        *(float4*)&outb[r * HS + c1] = o1;
    }
}

// Per-row LayerNorm + ReLU, in place. thread (row=tid>>2, q=tid&3) owns 32 elems.
__device__ __forceinline__ void ln_relu(float* __restrict__ buf,
                                        const float* __restrict__ g,
                                        const float* __restrict__ be, int tid)
{
    const int row = tid >> 2, q = tid & 3;
    float* rb = buf + row * HS;
    float v[32];
    float sum = 0.f, sq = 0.f;
#pragma unroll
    for (int j = 0; j < 8; ++j) {
        float4 t = *(const float4*)(rb + j * 16 + q * 4);
        v[4 * j + 0] = t.x; v[4 * j + 1] = t.y;
        v[4 * j + 2] = t.z; v[4 * j + 3] = t.w;
        sum += t.x + t.y + t.z + t.w;
        sq  += t.x * t.x + t.y * t.y + t.z * t.z + t.w * t.w;
    }
    sum += __shfl_xor(sum, 1); sum += __shfl_xor(sum, 2);
    sq  += __shfl_xor(sq, 1);  sq  += __shfl_xor(sq, 2);
    const float mu   = sum * (1.0f / 128.0f);
    const float var  = sq * (1.0f / 128.0f) - mu * mu;
    const float rstd = rsqrtf(var + LN_EPS);
#pragma unroll
    for (int j = 0; j < 8; ++j) {
        int c = j * 16 + q * 4;
        float4 gw = *(const float4*)(g + c);
        float4 bw = *(const float4*)(be + c);
        float4 o;
        o.x = fmaxf(0.f, (v[4 * j + 0] - mu) * rstd * gw.x + bw.x);
        o.y = fmaxf(0.f, (v[4 * j + 1] - mu) * rstd * gw.y + bw.y);
        o.z = fmaxf(0.f, (v[4 * j + 2] - mu) * rstd * gw.z + bw.z);
        o.w = fmaxf(0.f, (v[4 * j + 3] - mu) * rstd * gw.w + bw.w);
        *(float4*)(rb + c) = o;
    }
}

// ---------------------------------------------------------------------------
// Kernel 2: fused  h=(1+eps)*x+agg -> [GEMM+LN+ReLU] x2 -> GEMM+b3
// Writes h3 to `out` (== d_out, same rows it read agg from — no cross-block
// hazard) and accumulates per-graph sum/sumsq/count into gstat.
// ---------------------------------------------------------------------------
__global__ __launch_bounds__(256) void fused_mlp_kernel(
    const float* __restrict__ node, const float* __restrict__ agg,
    const float* __restrict__ epsp,
    const float* __restrict__ W1, const float* __restrict__ W2,
    const float* __restrict__ W3,
    const float* __restrict__ b1, const float* __restrict__ g1,
    const float* __restrict__ be1,
    const float* __restrict__ b2, const float* __restrict__ g2,
    const float* __restrict__ be2,
    const float* __restrict__ b3, const int* __restrict__ batch,
    float* __restrict__ out, float* __restrict__ gstat)
{
    __shared__ float Ws[128 * 128];      // 64 KB
    __shared__ float hA[64 * HS];        // 33 KB
    __shared__ float hB[64 * HS];        // 33 KB
    __shared__ float prm[7 * 128];       // b1,g1,be1,b2,g2,be2,b3
    __shared__ float s_gsum[G_NUM], s_gsq[G_NUM], s_gcnt[G_NUM];

    const int tid = threadIdx.x;
    const size_t row0 = (size_t)blockIdx.x * 64;

    if (tid < G_NUM) { s_gsum[tid] = 0.f; s_gsq[tid] = 0.f; s_gcnt[tid] = 0.f; }

    {   // stage params
        const float* srcs[7] = {b1, g1, be1, b2, g2, be2, b3};
#pragma unroll
        for (int t = 0; t < 4; ++t) {
            int i = tid + t * 256;
            if (i < 7 * 128) prm[i] = srcs[i >> 7][i & 127];
        }
    }
    stageW(Ws, W1, tid);

    // stage input rows: hA = (1+eps)*node + agg   (zero-pad past N)
    const float epsv = 1.0f + epsp[0];
#pragma unroll
    for (int j = 0; j < 8; ++j) {
        int idx4 = tid + j * 256;          // 2048 float4 = 64 rows x 32
        int r = idx4 >> 5, c4 = idx4 & 31;
        size_t nrow = row0 + r;
        float4 v = make_float4(0.f, 0.f, 0.f, 0.f);
        if (nrow < N_NODES) {
            float4 a = ((const float4*)(node + nrow * H))[c4];
            float4 b = ((const float4*)(agg + nrow * H))[c4];
            v.x = epsv * a.x + b.x; v.y = epsv * a.y + b.y;
            v.z = epsv * a.z + b.z; v.w = epsv * a.w + b.w;
        }
        *(float4*)&hA[r * HS + c4 * 4] = v;
    }
    __syncthreads();

    // layer 1
    gemm_tile(hA, hB, Ws, &prm[0], tid);
    __syncthreads();
    ln_relu(hB, &prm[128], &prm[256], tid);
    stageW(Ws, W2, tid);
    __syncthreads();

    // layer 2
    gemm_tile(hB, hA, Ws, &prm[384], tid);
    __syncthreads();
    ln_relu(hA, &prm[512], &prm[640], tid);
    stageW(Ws, W3, tid);
    __syncthreads();

    // layer 3: GEMM + b3, write to global, accumulate per-graph stats
    {
        const int cc = tid & 15;
        const int rr = tid >> 4;
        const int c0 = 4 * cc, c1 = 64 + 4 * cc;
        float acc[4][8];
#pragma unroll
        for (int i = 0; i < 4; ++i)
#pragma unroll
            for (int j = 0; j < 8; ++j) acc[i][j] = 0.f;

        const float* in0 = hA + (4 * rr + 0) * HS;
        const float* in1 = hA + (4 * rr + 1) * HS;
        const float* in2 = hA + (4 * rr + 2) * HS;
        const float* in3 = hA + (4 * rr + 3) * HS;
        for (int k = 0; k < 128; k += 4) {
            float4 a0 = *(const float4*)(in0 + k);
            float4 a1 = *(const float4*)(in1 + k);
            float4 a2 = *(const float4*)(in2 + k);
            float4 a3 = *(const float4*)(in3 + k);
            float ar[4][4] = {{a0.x, a0.y, a0.z, a0.w},
                              {a1.x, a1.y, a1.z, a1.w},
                              {a2.x, a2.y, a2.z, a2.w},
                              {a3.x, a3.y, a3.z, a3.w}};
#pragma unroll
            for (int kk = 0; kk < 4; ++kk) {
                float4 w0 = *(const float4*)&Ws[(k + kk) * 128 + c0];
                float4 w1 = *(const float4*)&Ws[(k + kk) * 128 + c1];
                float wv[8] = {w0.x, w0.y, w0.z, w0.w, w1.x, w1.y, w1.z, w1.w};
#pragma unroll
                for (int i = 0; i < 4; ++i) {
                    float av = ar[i][kk];
#pragma unroll
                    for (int j = 0; j < 8; ++j)
                        acc[i][j] = fmaf(av, wv[j], acc[i][j]);
                }
            }
        }
        float4 bb0 = *(const float4*)&prm[768 + c0];
        float4 bb1 = *(const float4*)&prm[768 + c1];
#pragma unroll
        for (int i = 0; i < 4; ++i) {
            size_t nrow = row0 + 4 * rr + i;
            float4 o0 = make_float4(acc[i][0] + bb0.x, acc[i][1] + bb0.y,
                                    acc[i][2] + bb0.z, acc[i][3] + bb0.w);
            float4 o1 = make_float4(acc[i][4] + bb1.x, acc[i][5] + bb1.y,
                                    acc[i][6] + bb1.z, acc[i][7] + bb1.w);
            float rsum = o0.x + o0.y + o0.z + o0.w + o1.x + o1.y + o1.z + o1.w;
            float rsq  = o0.x * o0.x + o0.y * o0.y + o0.z * o0.z + o0.w * o0.w +
                         o1.x * o1.x + o1.y * o1.y + o1.z * o1.z + o1.w * o1.w;
#pragma unroll
            for (int m = 1; m < 16; m <<= 1) {     // reduce over the 16 cc lanes
                rsum += __shfl_xor(rsum, m);
                rsq  += __shfl_xor(rsq, m);
            }
            if (nrow < N_NODES) {
                *(float4*)&out[nrow * H + c0] = o0;
                *(float4*)&out[nrow * H + c1] = o1;
                if (cc == 0) {
                    int g = batch[nrow];
                    atomicAdd(&s_gsum[g], rsum);
                    atomicAdd(&s_gsq[g], rsq);
                    atomicAdd(&s_gcnt[g], 1.0f);
                }
            }
        }
    }
    __syncthreads();
    if (tid < G_NUM && s_gcnt[tid] > 0.f) {
        unsafeAtomicAdd(&gstat[tid], s_gsum[tid]);
        unsafeAtomicAdd(&gstat[G_NUM + tid], s_gsq[tid]);
        unsafeAtomicAdd(&gstat[2 * G_NUM + tid], s_gcnt[tid]);
    }
}

// ---------------------------------------------------------------------------
// Kernel 3: finalize per-graph mean / inv-std
// ---------------------------------------------------------------------------
__global__ void finalize_stats_kernel(float* __restrict__ gstat)
{
    int g = threadIdx.x;
    if (g < G_NUM) {
        float cnt  = gstat[2 * G_NUM + g];
        float norm = fmaxf(cnt * (float)H, 1.0f);
        float mean = gstat[g] / norm;
        float var  = gstat[G_NUM + g] / norm - mean * mean;
        gstat[3 * G_NUM + g] = mean;
        gstat[4 * G_NUM + g] = rsqrtf(var + LN_EPS);
    }
}

// ---------------------------------------------------------------------------
// Kernel 4: graph-LN apply + ReLU, in place on d_out
// ---------------------------------------------------------------------------
__global__ __launch_bounds__(256) void final_ln_kernel(
    float* __restrict__ h3, const int* __restrict__ batch,
    const float* __restrict__ lnw, const float* __restrict__ lnb,
    const float* __restrict__ gstat)
{
    int idx4 = blockIdx.x * 256 + threadIdx.x;    // N*32 total
    if (idx4 >= N_NODES * 32) return;
    int node = idx4 >> 5;
    int c4 = (idx4 & 31) * 4;
    int g = batch[node];
    float mean = gstat[3 * G_NUM + g];
    float inv  = gstat[4 * G_NUM + g];
    float4 v = ((const float4*)h3)[idx4];
    float4 w = *(const float4*)&lnw[c4];
    float4 b = *(const float4*)&lnb[c4];
    v.x = fmaxf(0.f, (v.x - mean) * inv * w.x + b.x);
    v.y = fmaxf(0.f, (v.y - mean) * inv * w.y + b.y);
    v.z = fmaxf(0.f, (v.z - mean) * inv * w.z + b.z);
    v.w = fmaxf(0.f, (v.w - mean) * inv * w.w + b.w);
    ((float4*)h3)[idx4] = v;
}

// ---------------------------------------------------------------------------
extern "C" void kernel_launch(void* const* d_in, const int* in_sizes, int n_in,
                              void* d_out, int out_size, void* d_ws, size_t ws_size,
                              hipStream_t stream)
{
    const float* node  = (const float*)d_in[0];
    const int*   ei    = (const int*)d_in[1];
    // d_in[2] = edge_attr (unused)
    const int*   batch = (const int*)d_in[3];
    const float* epsp  = (const float*)d_in[4];
    const float* W1    = (const float*)d_in[5];
    const float* b1    = (const float*)d_in[6];
    const float* g1    = (const float*)d_in[7];
    const float* be1   = (const float*)d_in[8];
    const float* W2    = (const float*)d_in[9];
    const float* b2    = (const float*)d_in[10];
    const float* g2    = (const float*)d_in[11];
    const float* be2   = (const float*)d_in[12];
    const float* W3    = (const float*)d_in[13];
    const float* b3    = (const float*)d_in[14];
    const float* lnw   = (const float*)d_in[15];
    const float* lnb   = (const float*)d_in[16];

    float* out   = (float*)d_out;
    float* gstat = (float*)d_ws;           // 5*64 floats: sum, sq, cnt, mean, inv

    // d_out doubles as the agg accumulator (each MLP block reads its own rows
    // before overwriting them) — zero it; zero graph stats.
    hipMemsetAsync(d_out, 0, (size_t)N_NODES * H * sizeof(float), stream);
    hipMemsetAsync(d_ws, 0, 5 * G_NUM * sizeof(float), stream);

    scatter_add_kernel<<<(N_EDGES * 32) / 256, 256, 0, stream>>>(node, ei, out);

    fused_mlp_kernel<<<(N_NODES + 63) / 64, 256, 0, stream>>>(
        node, out, epsp, W1, W2, W3, b1, g1, be1, b2, g2, be2, b3, batch,
        out, gstat);

    finalize_stats_kernel<<<1, 64, 0, stream>>>(gstat);

    final_ln_kernel<<<(N_NODES * 32 + 255) / 256, 256, 0, stream>>>(
        out, batch, lnw, lnb, gstat);
}

// Round 2
// 488.205 us; speedup vs baseline: 2.8405x; 2.8405x over previous
//
#include <hip/hip_runtime.h>

#define N_NODES 100000
#define N_EDGES 600000
#define H 128
#define G_NUM 64
#define LN_EPS 1e-5f

// LDS h-buffer row stride: 132 keeps float4 alignment for every row and
// gives <=2-way bank aliasing on the k-loop reads.
#define HS 132

// CSR-build scan geometry
#define SCAN_CHUNK 1024
#define SCAN_NB ((N_NODES + SCAN_CHUNK - 1) / SCAN_CHUNK)   // 98

// ---------------------------------------------------------------------------
// CSR build kernel 1: in-degree histogram (int atomics, 600k total)
// ---------------------------------------------------------------------------
__global__ __launch_bounds__(256) void hist_kernel(
    const int* __restrict__ ei, int* __restrict__ deg)
{
    int e = blockIdx.x * 256 + threadIdx.x;
    if (e >= N_EDGES) return;
    atomicAdd(&deg[ei[N_EDGES + e]], 1);
}

// ---------------------------------------------------------------------------
// CSR build kernel 2: per-block exclusive scan (1024 elems/block)
// ---------------------------------------------------------------------------
__global__ __launch_bounds__(256) void scan1_kernel(
    const int* __restrict__ deg, int* __restrict__ off,
    int* __restrict__ blksum)
{
    __shared__ int sA[256], sB[256];
    const int tid = threadIdx.x;
    const int base = blockIdx.x * SCAN_CHUNK + tid * 4;
    int v[4];
#pragma unroll
    for (int j = 0; j < 4; ++j) {
        int i = base + j;
        v[j] = (i < N_NODES) ? deg[i] : 0;
    }
    int tsum = v[0] + v[1] + v[2] + v[3];
    int* a = sA; int* b = sB;
    a[tid] = tsum;
    __syncthreads();
#pragma unroll
    for (int o = 1; o < 256; o <<= 1) {
        int t = a[tid] + ((tid >= o) ? a[tid - o] : 0);
        b[tid] = t;
        __syncthreads();
        int* tmp = a; a = b; b = tmp;
    }
    int run = a[tid] - tsum;            // exclusive prefix for this thread
#pragma unroll
    for (int j = 0; j < 4; ++j) {
        int i = base + j;
        if (i < N_NODES) off[i] = run;
        run += v[j];
    }
    if (tid == 255) blksum[blockIdx.x] = a[255];
}

// ---------------------------------------------------------------------------
// CSR build kernel 3: scan the 98 block totals (single block)
// ---------------------------------------------------------------------------
__global__ __launch_bounds__(128) void scan2_kernel(int* __restrict__ blksum)
{
    __shared__ int sA[128], sB[128];
    const int tid = threadIdx.x;
    int v = (tid < SCAN_NB) ? blksum[tid] : 0;
    int* a = sA; int* b = sB;
    a[tid] = v;
    __syncthreads();
#pragma unroll
    for (int o = 1; o < 128; o <<= 1) {
        int t = a[tid] + ((tid >= o) ? a[tid - o] : 0);
        b[tid] = t;
        __syncthreads();
        int* tmp = a; a = b; b = tmp;
    }
    if (tid < SCAN_NB) blksum[tid] = a[tid] - v;   // exclusive
}

// ---------------------------------------------------------------------------
// CSR build kernel 4: add block offsets; init cursor; set off[N]=E
// ---------------------------------------------------------------------------
__global__ __launch_bounds__(256) void scan3_kernel(
    int* __restrict__ off, const int* __restrict__ blksum,
    int* __restrict__ cursor)
{
    int i = blockIdx.x * 256 + threadIdx.x;
    if (i < N_NODES) {
        int val = off[i] + blksum[i >> 10];
        off[i] = val;
        cursor[i] = val;
    }
    if (i == 0) off[N_NODES] = N_EDGES;
}

// ---------------------------------------------------------------------------
// CSR build kernel 5: fill edge lists (csr[pos] = src, grouped by dst)
// ---------------------------------------------------------------------------
__global__ __launch_bounds__(256) void fill_kernel(
    const int* __restrict__ ei, int* __restrict__ cursor,
    int* __restrict__ csr)
{
    int e = blockIdx.x * 256 + threadIdx.x;
    if (e >= N_EDGES) return;
    int dst = ei[N_EDGES + e];
    int pos = atomicAdd(&cursor[dst], 1);
    csr[pos] = ei[e];
}

// ---------------------------------------------------------------------------
// Gather kernel: one wave per node, float2 per lane. agg[n] = sum node[src].
// Replaces 76.8M fp32 atomics with coalesced 512B row reads (LLC-resident).
// ---------------------------------------------------------------------------
__global__ __launch_bounds__(256) void gather_kernel(
    const float* __restrict__ node, const int* __restrict__ off,
    const int* __restrict__ csr, float* __restrict__ agg)
{
    int wid = (blockIdx.x * 256 + threadIdx.x) >> 6;   // node id
    int lane = threadIdx.x & 63;
    if (wid >= N_NODES) return;
    int s0 = off[wid], s1 = off[wid + 1];
    const float2* np = (const float2*)node;
    float2 acc = make_float2(0.f, 0.f);
    int j = s0;
    for (; j + 1 < s1; j += 2) {       // 2 rows in flight
        int a = csr[j], b = csr[j + 1];
        float2 va = np[(size_t)a * 64 + lane];
        float2 vb = np[(size_t)b * 64 + lane];
        acc.x += va.x; acc.y += va.y;
        acc.x += vb.x; acc.y += vb.y;
    }
    if (j < s1) {
        int a = csr[j];
        float2 va = np[(size_t)a * 64 + lane];
        acc.x += va.x; acc.y += va.y;
    }
    ((float2*)agg)[(size_t)wid * 64 + lane] = acc;
}

// ---------------------------------------------------------------------------
// Fused 3-layer MLP helpers (unchanged from round 1)
// ---------------------------------------------------------------------------
__device__ __forceinline__ void stageW(float* __restrict__ Ws,
                                       const float* __restrict__ W, int tid)
{
#pragma unroll
    for (int j = 0; j < 16; ++j) {
        int idx4 = tid + j * 256;                 // 4096 float4 = 128x128
        ((float4*)Ws)[idx4] = ((const float4*)W)[idx4];
    }
}

__device__ __forceinline__ void gemm_tile(const float* __restrict__ inb,
                                          float* __restrict__ outb,
                                          const float* __restrict__ Ws,
                                          const float* __restrict__ bias, int tid)
{
    const int cc = tid & 15;
    const int rr = tid >> 4;
    const int c0 = 4 * cc, c1 = 64 + 4 * cc;
    float acc[4][8];
#pragma unroll
    for (int i = 0; i < 4; ++i)
#pragma unroll
        for (int j = 0; j < 8; ++j) acc[i][j] = 0.f;

    const float* in0 = inb + (4 * rr + 0) * HS;
    const float* in1 = inb + (4 * rr + 1) * HS;
    const float* in2 = inb + (4 * rr + 2) * HS;
    const float* in3 = inb + (4 * rr + 3) * HS;

    for (int k = 0; k < 128; k += 4) {
        float4 a0 = *(const float4*)(in0 + k);
        float4 a1 = *(const float4*)(in1 + k);
        float4 a2 = *(const float4*)(in2 + k);
        float4 a3 = *(const float4*)(in3 + k);
        float ar[4][4] = {{a0.x, a0.y, a0.z, a0.w},
                          {a1.x, a1.y, a1.z, a1.w},
                          {a2.x, a2.y, a2.z, a2.w},
                          {a3.x, a3.y, a3.z, a3.w}};
#pragma unroll
        for (int kk = 0; kk < 4; ++kk) {
            float4 w0 = *(const float4*)&Ws[(k + kk) * 128 + c0];
            float4 w1 = *(const float4*)&Ws[(k + kk) * 128 + c1];
            float wv[8] = {w0.x, w0.y, w0.z, w0.w, w1.x, w1.y, w1.z, w1.w};
#pragma unroll
            for (int i = 0; i < 4; ++i) {
                float av = ar[i][kk];
#pragma unroll
                for (int j = 0; j < 8; ++j)
                    acc[i][j] = fmaf(av, wv[j], acc[i][j]);
            }
        }
    }
    float4 bb0 = *(const float4*)&bias[c0];
    float4 bb1 = *(const float4*)&bias[c1];
#pragma unroll
    for (int i = 0; i < 4; ++i) {
        int r = 4 * rr + i;
        float4 o0 = make_float4(acc[i][0] + bb0.x, acc[i][1] + bb0.y,
                                acc[i][2] + bb0.z, acc[i][3] + bb0.w);
        float4 o1 = make_float4(acc[i][4] + bb1.x, acc[i][5] + bb1.y,
                                acc[i][6] + bb1.z, acc[i][7] + bb1.w);
        *(float4*)&outb[r * HS + c0] = o0;
        *(float4*)&outb[r * HS + c1] = o1;
    }
}

__device__ __forceinline__ void ln_relu(float* __restrict__ buf,
                                        const float* __restrict__ g,
                                        const float* __restrict__ be, int tid)
{
    const int row = tid >> 2, q = tid & 3;
    float* rb = buf + row * HS;
    float v[32];
    float sum = 0.f, sq = 0.f;
#pragma unroll
    for (int j = 0; j < 8; ++j) {
        float4 t = *(const float4*)(rb + j * 16 + q * 4);
        v[4 * j + 0] = t.x; v[4 * j + 1] = t.y;
        v[4 * j + 2] = t.z; v[4 * j + 3] = t.w;
        sum += t.x + t.y + t.z + t.w;
        sq  += t.x * t.x + t.y * t.y + t.z * t.z + t.w * t.w;
    }
    sum += __shfl_xor(sum, 1); sum += __shfl_xor(sum, 2);
    sq  += __shfl_xor(sq, 1);  sq  += __shfl_xor(sq, 2);
    const float mu   = sum * (1.0f / 128.0f);
    const float var  = sq * (1.0f / 128.0f) - mu * mu;
    const float rstd = rsqrtf(var + LN_EPS);
#pragma unroll
    for (int j = 0; j < 8; ++j) {
        int c = j * 16 + q * 4;
        float4 gw = *(const float4*)(g + c);
        float4 bw = *(const float4*)(be + c);
        float4 o;
        o.x = fmaxf(0.f, (v[4 * j + 0] - mu) * rstd * gw.x + bw.x);
        o.y = fmaxf(0.f, (v[4 * j + 1] - mu) * rstd * gw.y + bw.y);
        o.z = fmaxf(0.f, (v[4 * j + 2] - mu) * rstd * gw.z + bw.z);
        o.w = fmaxf(0.f, (v[4 * j + 3] - mu) * rstd * gw.w + bw.w);
        *(float4*)(rb + c) = o;
    }
}

// ---------------------------------------------------------------------------
// Fused MLP (unchanged): h=(1+eps)*x+agg -> [GEMM+LN+ReLU] x2 -> GEMM+b3
// ---------------------------------------------------------------------------
__global__ __launch_bounds__(256) void fused_mlp_kernel(
    const float* __restrict__ node, const float* __restrict__ agg,
    const float* __restrict__ epsp,
    const float* __restrict__ W1, const float* __restrict__ W2,
    const float* __restrict__ W3,
    const float* __restrict__ b1, const float* __restrict__ g1,
    const float* __restrict__ be1,
    const float* __restrict__ b2, const float* __restrict__ g2,
    const float* __restrict__ be2,
    const float* __restrict__ b3, const int* __restrict__ batch,
    float* __restrict__ out, float* __restrict__ gstat)
{
    __shared__ float Ws[128 * 128];      // 64 KB
    __shared__ float hA[64 * HS];        // 33 KB
    __shared__ float hB[64 * HS];        // 33 KB
    __shared__ float prm[7 * 128];
    __shared__ float s_gsum[G_NUM], s_gsq[G_NUM], s_gcnt[G_NUM];

    const int tid = threadIdx.x;
    const size_t row0 = (size_t)blockIdx.x * 64;

    if (tid < G_NUM) { s_gsum[tid] = 0.f; s_gsq[tid] = 0.f; s_gcnt[tid] = 0.f; }

    {
        const float* srcs[7] = {b1, g1, be1, b2, g2, be2, b3};
#pragma unroll
        for (int t = 0; t < 4; ++t) {
            int i = tid + t * 256;
            if (i < 7 * 128) prm[i] = srcs[i >> 7][i & 127];
        }
    }
    stageW(Ws, W1, tid);

    const float epsv = 1.0f + epsp[0];
#pragma unroll
    for (int j = 0; j < 8; ++j) {
        int idx4 = tid + j * 256;
        int r = idx4 >> 5, c4 = idx4 & 31;
        size_t nrow = row0 + r;
        float4 v = make_float4(0.f, 0.f, 0.f, 0.f);
        if (nrow < N_NODES) {
            float4 a = ((const float4*)(node + nrow * H))[c4];
            float4 b = ((const float4*)(agg + nrow * H))[c4];
            v.x = epsv * a.x + b.x; v.y = epsv * a.y + b.y;
            v.z = epsv * a.z + b.z; v.w = epsv * a.w + b.w;
        }
        *(float4*)&hA[r * HS + c4 * 4] = v;
    }
    __syncthreads();

    gemm_tile(hA, hB, Ws, &prm[0], tid);
    __syncthreads();
    ln_relu(hB, &prm[128], &prm[256], tid);
    stageW(Ws, W2, tid);
    __syncthreads();

    gemm_tile(hB, hA, Ws, &prm[384], tid);
    __syncthreads();
    ln_relu(hA, &prm[512], &prm[640], tid);
    stageW(Ws, W3, tid);
    __syncthreads();

    {
        const int cc = tid & 15;
        const int rr = tid >> 4;
        const int c0 = 4 * cc, c1 = 64 + 4 * cc;
        float acc[4][8];
#pragma unroll
        for (int i = 0; i < 4; ++i)
#pragma unroll
            for (int j = 0; j < 8; ++j) acc[i][j] = 0.f;

        const float* in0 = hA + (4 * rr + 0) * HS;
        const float* in1 = hA + (4 * rr + 1) * HS;
        const float* in2 = hA + (4 * rr + 2) * HS;
        const float* in3 = hA + (4 * rr + 3) * HS;
        for (int k = 0; k < 128; k += 4) {
            float4 a0 = *(const float4*)(in0 + k);
            float4 a1 = *(const float4*)(in1 + k);
            float4 a2 = *(const float4*)(in2 + k);
            float4 a3 = *(const float4*)(in3 + k);
            float ar[4][4] = {{a0.x, a0.y, a0.z, a0.w},
                              {a1.x, a1.y, a1.z, a1.w},
                              {a2.x, a2.y, a2.z, a2.w},
                              {a3.x, a3.y, a3.z, a3.w}};
#pragma unroll
            for (int kk = 0; kk < 4; ++kk) {
                float4 w0 = *(const float4*)&Ws[(k + kk) * 128 + c0];
                float4 w1 = *(const float4*)&Ws[(k + kk) * 128 + c1];
                float wv[8] = {w0.x, w0.y, w0.z, w0.w, w1.x, w1.y, w1.z, w1.w};
#pragma unroll
                for (int i = 0; i < 4; ++i) {
                    float av = ar[i][kk];
#pragma unroll
                    for (int j = 0; j < 8; ++j)
                        acc[i][j] = fmaf(av, wv[j], acc[i][j]);
                }
            }
        }
        float4 bb0 = *(const float4*)&prm[768 + c0];
        float4 bb1 = *(const float4*)&prm[768 + c1];
#pragma unroll
        for (int i = 0; i < 4; ++i) {
            size_t nrow = row0 + 4 * rr + i;
            float4 o0 = make_float4(acc[i][0] + bb0.x, acc[i][1] + bb0.y,
                                    acc[i][2] + bb0.z, acc[i][3] + bb0.w);
            float4 o1 = make_float4(acc[i][4] + bb1.x, acc[i][5] + bb1.y,
                                    acc[i][6] + bb1.z, acc[i][7] + bb1.w);
            float rsum = o0.x + o0.y + o0.z + o0.w + o1.x + o1.y + o1.z + o1.w;
            float rsq  = o0.x * o0.x + o0.y * o0.y + o0.z * o0.z + o0.w * o0.w +
                         o1.x * o1.x + o1.y * o1.y + o1.z * o1.z + o1.w * o1.w;
#pragma unroll
            for (int m = 1; m < 16; m <<= 1) {
                rsum += __shfl_xor(rsum, m);
                rsq  += __shfl_xor(rsq, m);
            }
            if (nrow < N_NODES) {
                *(float4*)&out[nrow * H + c0] = o0;
                *(float4*)&out[nrow * H + c1] = o1;
                if (cc == 0) {
                    int g = batch[nrow];
                    atomicAdd(&s_gsum[g], rsum);
                    atomicAdd(&s_gsq[g], rsq);
                    atomicAdd(&s_gcnt[g], 1.0f);
                }
            }
        }
    }
    __syncthreads();
    if (tid < G_NUM && s_gcnt[tid] > 0.f) {
        unsafeAtomicAdd(&gstat[tid], s_gsum[tid]);
        unsafeAtomicAdd(&gstat[G_NUM + tid], s_gsq[tid]);
        unsafeAtomicAdd(&gstat[2 * G_NUM + tid], s_gcnt[tid]);
    }
}

// ---------------------------------------------------------------------------
__global__ void finalize_stats_kernel(float* __restrict__ gstat)
{
    int g = threadIdx.x;
    if (g < G_NUM) {
        float cnt  = gstat[2 * G_NUM + g];
        float norm = fmaxf(cnt * (float)H, 1.0f);
        float mean = gstat[g] / norm;
        float var  = gstat[G_NUM + g] / norm - mean * mean;
        gstat[3 * G_NUM + g] = mean;
        gstat[4 * G_NUM + g] = rsqrtf(var + LN_EPS);
    }
}

// ---------------------------------------------------------------------------
__global__ __launch_bounds__(256) void final_ln_kernel(
    float* __restrict__ h3, const int* __restrict__ batch,
    const float* __restrict__ lnw, const float* __restrict__ lnb,
    const float* __restrict__ gstat)
{
    int idx4 = blockIdx.x * 256 + threadIdx.x;
    if (idx4 >= N_NODES * 32) return;
    int node = idx4 >> 5;
    int c4 = (idx4 & 31) * 4;
    int g = batch[node];
    float mean = gstat[3 * G_NUM + g];
    float inv  = gstat[4 * G_NUM + g];
    float4 v = ((const float4*)h3)[idx4];
    float4 w = *(const float4*)&lnw[c4];
    float4 b = *(const float4*)&lnb[c4];
    v.x = fmaxf(0.f, (v.x - mean) * inv * w.x + b.x);
    v.y = fmaxf(0.f, (v.y - mean) * inv * w.y + b.y);
    v.z = fmaxf(0.f, (v.z - mean) * inv * w.z + b.z);
    v.w = fmaxf(0.f, (v.w - mean) * inv * w.w + b.w);
    ((float4*)h3)[idx4] = v;
}

// ---------------------------------------------------------------------------
extern "C" void kernel_launch(void* const* d_in, const int* in_sizes, int n_in,
                              void* d_out, int out_size, void* d_ws, size_t ws_size,
                              hipStream_t stream)
{
    const float* node  = (const float*)d_in[0];
    const int*   ei    = (const int*)d_in[1];
    // d_in[2] = edge_attr (unused)
    const int*   batch = (const int*)d_in[3];
    const float* epsp  = (const float*)d_in[4];
    const float* W1    = (const float*)d_in[5];
    const float* b1    = (const float*)d_in[6];
    const float* g1    = (const float*)d_in[7];
    const float* be1   = (const float*)d_in[8];
    const float* W2    = (const float*)d_in[9];
    const float* b2    = (const float*)d_in[10];
    const float* g2    = (const float*)d_in[11];
    const float* be2   = (const float*)d_in[12];
    const float* W3    = (const float*)d_in[13];
    const float* b3    = (const float*)d_in[14];
    const float* lnw   = (const float*)d_in[15];
    const float* lnb   = (const float*)d_in[16];

    float* out   = (float*)d_out;

    // Workspace layout (ints after a 512-float gstat slot): ~3.6 MB total
    float* gstat  = (float*)d_ws;                    // 5*64 floats used
    int*   deg    = (int*)d_ws + 512;                // N
    int*   off    = deg + N_NODES;                   // N+1
    int*   cursor = off + N_NODES + 1;               // N
    int*   csr    = cursor + N_NODES;                // E
    int*   blksum = csr + N_EDGES;                   // SCAN_NB

    hipMemsetAsync(gstat, 0, 5 * G_NUM * sizeof(float), stream);
    hipMemsetAsync(deg, 0, N_NODES * sizeof(int), stream);

    // --- CSR build (by dst) ---
    hist_kernel<<<(N_EDGES + 255) / 256, 256, 0, stream>>>(ei, deg);
    scan1_kernel<<<SCAN_NB, 256, 0, stream>>>(deg, off, blksum);
    scan2_kernel<<<1, 128, 0, stream>>>(blksum);
    scan3_kernel<<<(N_NODES + 255) / 256, 256, 0, stream>>>(off, blksum, cursor);
    fill_kernel<<<(N_EDGES + 255) / 256, 256, 0, stream>>>(ei, cursor, csr);

    // --- Gather (replaces fp32 atomic scatter); writes agg into d_out ---
    gather_kernel<<<(N_NODES + 3) / 4, 256, 0, stream>>>(node, off, csr, out);

    // --- Fused MLP (reads agg from d_out rows, overwrites with h3) ---
    fused_mlp_kernel<<<(N_NODES + 63) / 64, 256, 0, stream>>>(
        node, out, epsp, W1, W2, W3, b1, g1, be1, b2, g2, be2, b3, batch,
        out, gstat);

    finalize_stats_kernel<<<1, 64, 0, stream>>>(gstat);

    final_ln_kernel<<<(N_NODES * 32 + 255) / 256, 256, 0, stream>>>(
        out, batch, lnw, lnb, gstat);
}

// Round 3
// 438.718 us; speedup vs baseline: 3.1609x; 1.1128x over previous
//
#include <hip/hip_runtime.h>

#define N_NODES 100000
#define N_EDGES 600000
#define H 128
#define G_NUM 64
#define LN_EPS 1e-5f

// LDS bf16 row stride: 136 bf16 = 272 B = 68 dwords -> bank step 4 per row,
// b128 frag reads land 8 lanes/bank-group = the 8-cycle minimum (conflict-free).
#define WSTR 136

// CSR-build scan geometry
#define SCAN_CHUNK 1024
#define SCAN_NB ((N_NODES + SCAN_CHUNK - 1) / SCAN_CHUNK)   // 98

typedef __attribute__((ext_vector_type(8))) short short8;   // 8 bf16 (4 VGPRs)
typedef __attribute__((ext_vector_type(4))) float floatx4;  // MFMA C/D

__device__ __forceinline__ unsigned short f2bf(float x) {   // RNE fp32->bf16
    unsigned int u = __float_as_uint(x);
    u += 0x7fffu + ((u >> 16) & 1u);
    return (unsigned short)(u >> 16);
}
__device__ __forceinline__ float bf2f(unsigned short h) {
    return __uint_as_float(((unsigned int)h) << 16);
}

// ---------------------------------------------------------------------------
// CSR build (unchanged from round 2)
// ---------------------------------------------------------------------------
__global__ __launch_bounds__(256) void hist_kernel(
    const int* __restrict__ ei, int* __restrict__ deg)
{
    int e = blockIdx.x * 256 + threadIdx.x;
    if (e >= N_EDGES) return;
    atomicAdd(&deg[ei[N_EDGES + e]], 1);
}

__global__ __launch_bounds__(256) void scan1_kernel(
    const int* __restrict__ deg, int* __restrict__ off,
    int* __restrict__ blksum)
{
    __shared__ int sA[256], sB[256];
    const int tid = threadIdx.x;
    const int base = blockIdx.x * SCAN_CHUNK + tid * 4;
    int v[4];
#pragma unroll
    for (int j = 0; j < 4; ++j) {
        int i = base + j;
        v[j] = (i < N_NODES) ? deg[i] : 0;
    }
    int tsum = v[0] + v[1] + v[2] + v[3];
    int* a = sA; int* b = sB;
    a[tid] = tsum;
    __syncthreads();
#pragma unroll
    for (int o = 1; o < 256; o <<= 1) {
        int t = a[tid] + ((tid >= o) ? a[tid - o] : 0);
        b[tid] = t;
        __syncthreads();
        int* tmp = a; a = b; b = tmp;
    }
    int run = a[tid] - tsum;
#pragma unroll
    for (int j = 0; j < 4; ++j) {
        int i = base + j;
        if (i < N_NODES) off[i] = run;
        run += v[j];
    }
    if (tid == 255) blksum[blockIdx.x] = a[255];
}

__global__ __launch_bounds__(128) void scan2_kernel(int* __restrict__ blksum)
{
    __shared__ int sA[128], sB[128];
    const int tid = threadIdx.x;
    int v = (tid < SCAN_NB) ? blksum[tid] : 0;
    int* a = sA; int* b = sB;
    a[tid] = v;
    __syncthreads();
#pragma unroll
    for (int o = 1; o < 128; o <<= 1) {
        int t = a[tid] + ((tid >= o) ? a[tid - o] : 0);
        b[tid] = t;
        __syncthreads();
        int* tmp = a; a = b; b = tmp;
    }
    if (tid < SCAN_NB) blksum[tid] = a[tid] - v;
}

__global__ __launch_bounds__(256) void scan3_kernel(
    int* __restrict__ off, const int* __restrict__ blksum,
    int* __restrict__ cursor)
{
    int i = blockIdx.x * 256 + threadIdx.x;
    if (i < N_NODES) {
        int val = off[i] + blksum[i >> 10];
        off[i] = val;
        cursor[i] = val;
    }
    if (i == 0) off[N_NODES] = N_EDGES;
}

__global__ __launch_bounds__(256) void fill_kernel(
    const int* __restrict__ ei, int* __restrict__ cursor,
    int* __restrict__ csr)
{
    int e = blockIdx.x * 256 + threadIdx.x;
    if (e >= N_EDGES) return;
    int dst = ei[N_EDGES + e];
    int pos = atomicAdd(&cursor[dst], 1);
    csr[pos] = ei[e];
}

// ---------------------------------------------------------------------------
// Weight prep: WT[l][n][k] = bf16(Wl[k][n])  (3 x 128x128, once per launch)
// ---------------------------------------------------------------------------
__global__ __launch_bounds__(256) void wt_prep_kernel(
    const float* __restrict__ W1, const float* __restrict__ W2,
    const float* __restrict__ W3, unsigned short* __restrict__ WT)
{
    int idx = blockIdx.x * 256 + threadIdx.x;       // 3*16384
    if (idx >= 3 * 16384) return;
    int l = idx >> 14, r = idx & 16383;
    int k = r >> 7, n = r & 127;
    const float* W = (l == 0) ? W1 : ((l == 1) ? W2 : W3);
    WT[l * 16384 + n * 128 + k] = f2bf(W[k * 128 + n]);
}

// ---------------------------------------------------------------------------
// MFMA MLP helpers
// ---------------------------------------------------------------------------
__device__ __forceinline__ void stageWb(unsigned short* __restrict__ Wb,
                                        const unsigned short* __restrict__ WT,
                                        int tid)
{
#pragma unroll
    for (int t = 0; t < 8; ++t) {
        int c = tid + t * 256;                 // 2048 chunks of 8 bf16
        int row = c >> 4, c8 = c & 15;
        *(short8*)&Wb[row * WSTR + c8 * 8] = *(const short8*)&WT[row * 128 + c8 * 8];
    }
}

// 16 rows x 128 cols per wave; D row = w*16+q*4+i, col = nt*16+c.
__device__ __forceinline__ void gemm_frags(const unsigned short* __restrict__ hIn,
                                           const unsigned short* __restrict__ Wb,
                                           floatx4 acc[8], int w, int lane)
{
    const int c = lane & 15, q = lane >> 4;
#pragma unroll
    for (int nt = 0; nt < 8; ++nt) acc[nt] = (floatx4){0.f, 0.f, 0.f, 0.f};
#pragma unroll
    for (int kt = 0; kt < 4; ++kt) {
        short8 a = *(const short8*)&hIn[(w * 16 + c) * WSTR + kt * 32 + q * 8];
#pragma unroll
        for (int nt = 0; nt < 8; ++nt) {
            short8 b = *(const short8*)&Wb[(nt * 16 + c) * WSTR + kt * 32 + q * 8];
            acc[nt] = __builtin_amdgcn_mfma_f32_16x16x32_bf16(a, b, acc[nt], 0, 0, 0);
        }
    }
}

// GEMM + bias -> bf16 back to LDS (layers 1 & 2)
__device__ __forceinline__ void gemm_layer(const unsigned short* __restrict__ hIn,
                                           unsigned short* __restrict__ hOut,
                                           const unsigned short* __restrict__ Wb,
                                           const float* __restrict__ bias,
                                           int w, int lane)
{
    const int c = lane & 15, q = lane >> 4;
    floatx4 acc[8];
    gemm_frags(hIn, Wb, acc, w, lane);
#pragma unroll
    for (int nt = 0; nt < 8; ++nt) {
        float bv = bias[nt * 16 + c];
#pragma unroll
        for (int i = 0; i < 4; ++i)
            hOut[(w * 16 + q * 4 + i) * WSTR + nt * 16 + c] = f2bf(acc[nt][i] + bv);
    }
}

// In-LDS per-row LayerNorm+ReLU on bf16 rows (each wave touches only its own
// 16 rows -> no cross-wave sync needed around this).
__device__ __forceinline__ void ln_pass(unsigned short* __restrict__ buf,
                                        const float* __restrict__ g,
                                        const float* __restrict__ be, int tid)
{
    const int row = tid >> 2, qt = tid & 3;      // 4 lanes/row, 32 cols each
    unsigned short* rb = buf + row * WSTR + qt * 32;
    float v[32];
    float sum = 0.f, sq = 0.f;
#pragma unroll
    for (int j = 0; j < 4; ++j) {
        short8 t = *(const short8*)&rb[j * 8];
#pragma unroll
        for (int e = 0; e < 8; ++e) {
            float f = bf2f((unsigned short)t[e]);
            v[j * 8 + e] = f; sum += f; sq += f * f;
        }
    }
    sum += __shfl_xor(sum, 1); sum += __shfl_xor(sum, 2);
    sq  += __shfl_xor(sq, 1);  sq  += __shfl_xor(sq, 2);
    const float mu   = sum * (1.0f / 128.0f);
    const float rstd = rsqrtf(sq * (1.0f / 128.0f) - mu * mu + LN_EPS);
#pragma unroll
    for (int j = 0; j < 4; ++j) {
        const float4 g0 = *(const float4*)&g[qt * 32 + j * 8];
        const float4 g1 = *(const float4*)&g[qt * 32 + j * 8 + 4];
        const float4 e0 = *(const float4*)&be[qt * 32 + j * 8];
        const float4 e1 = *(const float4*)&be[qt * 32 + j * 8 + 4];
        const float gw[8] = {g0.x, g0.y, g0.z, g0.w, g1.x, g1.y, g1.z, g1.w};
        const float bw[8] = {e0.x, e0.y, e0.z, e0.w, e1.x, e1.y, e1.z, e1.w};
        short8 o;
#pragma unroll
        for (int e = 0; e < 8; ++e) {
            float val = fmaxf(0.f, (v[j * 8 + e] - mu) * rstd * gw[e] + bw[e]);
            o[e] = (short)f2bf(val);
        }
        *(short8*)&rb[j * 8] = o;
    }
}

// ---------------------------------------------------------------------------
// Fused kernel: inline CSR gather -> bf16 h0 -> 3x MFMA GEMM (+LN x2)
//               -> fp32 out + per-graph stats
// ---------------------------------------------------------------------------
__global__ __launch_bounds__(256) void fused_mlp_kernel(
    const float* __restrict__ node, const int* __restrict__ off,
    const int* __restrict__ csr, const float* __restrict__ epsp,
    const unsigned short* __restrict__ WT,
    const float* __restrict__ b1, const float* __restrict__ g1,
    const float* __restrict__ be1,
    const float* __restrict__ b2, const float* __restrict__ g2,
    const float* __restrict__ be2,
    const float* __restrict__ b3, const int* __restrict__ batch,
    float* __restrict__ out, float* __restrict__ gstat)
{
    __shared__ unsigned short Wb[128 * WSTR];    // 34.8 KB
    __shared__ unsigned short hA[64 * WSTR];     // 17.4 KB
    __shared__ unsigned short hB[64 * WSTR];     // 17.4 KB
    __shared__ float prm[7 * 128];               // 3.6 KB  -> ~74 KB total, 2 blk/CU
    __shared__ float s_gsum[G_NUM], s_gsq[G_NUM], s_gcnt[G_NUM];

    const int tid = threadIdx.x;
    const int w = tid >> 6, lane = tid & 63;
    const size_t row0 = (size_t)blockIdx.x * 64;

    if (tid < G_NUM) { s_gsum[tid] = 0.f; s_gsq[tid] = 0.f; s_gcnt[tid] = 0.f; }
    {
        const float* srcs[7] = {b1, g1, be1, b2, g2, be2, b3};
#pragma unroll
        for (int t = 0; t < 4; ++t) {
            int i = tid + t * 256;
            if (i < 7 * 128) prm[i] = srcs[i >> 7][i & 127];
        }
    }
    stageWb(Wb, WT, tid);

    // inline gather: h0 = (1+eps)*x + sum_{src in N(n)} x_src, bf16 -> hA
    {
        const float2* np2 = (const float2*)node;
        const float epsv = 1.0f + epsp[0];
        for (int i = 0; i < 16; ++i) {
            const int r = w * 16 + i;
            const size_t n = row0 + r;
            unsigned int pack = 0u;
            if (n < N_NODES) {
                float2 own = np2[n * 64 + lane];
                const int s0 = off[n], s1 = off[n + 1];
                float ax = 0.f, ay = 0.f, bx = 0.f, by = 0.f;
                int j = s0;
                for (; j + 1 < s1; j += 2) {        // 2 rows in flight
                    int ea = csr[j], eb = csr[j + 1];
                    float2 va = np2[(size_t)ea * 64 + lane];
                    float2 vb = np2[(size_t)eb * 64 + lane];
                    ax += va.x; ay += va.y; bx += vb.x; by += vb.y;
                }
                if (j < s1) {
                    float2 va = np2[(size_t)csr[j] * 64 + lane];
                    ax += va.x; ay += va.y;
                }
                float hx = fmaf(epsv, own.x, ax + bx);
                float hy = fmaf(epsv, own.y, ay + by);
                pack = (unsigned)f2bf(hx) | ((unsigned)f2bf(hy) << 16);
            }
            ((unsigned int*)&hA[r * WSTR])[lane] = pack;   // cols 2*lane, 2*lane+1
        }
    }
    __syncthreads();                       // hA + Wb(W1) + prm ready

    gemm_layer(hA, hB, Wb, &prm[0], w, lane);
    ln_pass(hB, &prm[128], &prm[256], tid);   // own rows only
    __syncthreads();                       // all Wb(W1) reads drained
    stageWb(Wb, WT + 16384, tid);
    __syncthreads();                       // Wb(W2) ready

    gemm_layer(hB, hA, Wb, &prm[384], w, lane);
    ln_pass(hA, &prm[512], &prm[640], tid);
    __syncthreads();
    stageWb(Wb, WT + 32768, tid);
    __syncthreads();                       // Wb(W3) ready

    // layer 3: GEMM + b3 -> global fp32 + per-graph stats
    {
        const int c = lane & 15, q = lane >> 4;
        floatx4 acc[8];
        gemm_frags(hA, Wb, acc, w, lane);
        float sum[4] = {0.f, 0.f, 0.f, 0.f};
        float sq[4]  = {0.f, 0.f, 0.f, 0.f};
#pragma unroll
        for (int nt = 0; nt < 8; ++nt) {
            float bv = prm[768 + nt * 16 + c];
#pragma unroll
            for (int i = 0; i < 4; ++i) {
                float vv = acc[nt][i] + bv;
                size_t nrow = row0 + w * 16 + q * 4 + i;
                if (nrow < N_NODES)
                    out[nrow * H + nt * 16 + c] = vv;
                sum[i] += vv; sq[i] += vv * vv;
            }
        }
#pragma unroll
        for (int m = 1; m < 16; m <<= 1) {
#pragma unroll
            for (int i = 0; i < 4; ++i) {
                sum[i] += __shfl_xor(sum[i], m);
                sq[i]  += __shfl_xor(sq[i], m);
            }
        }
        if (c == 0) {
#pragma unroll
            for (int i = 0; i < 4; ++i) {
                size_t nrow = row0 + w * 16 + q * 4 + i;
                if (nrow < N_NODES) {
                    int g = batch[nrow];
                    atomicAdd(&s_gsum[g], sum[i]);
                    atomicAdd(&s_gsq[g], sq[i]);
                    atomicAdd(&s_gcnt[g], 1.0f);
                }
            }
        }
    }
    __syncthreads();
    if (tid < G_NUM && s_gcnt[tid] > 0.f) {
        unsafeAtomicAdd(&gstat[tid], s_gsum[tid]);
        unsafeAtomicAdd(&gstat[G_NUM + tid], s_gsq[tid]);
        unsafeAtomicAdd(&gstat[2 * G_NUM + tid], s_gcnt[tid]);
    }
}

// ---------------------------------------------------------------------------
__global__ void finalize_stats_kernel(float* __restrict__ gstat)
{
    int g = threadIdx.x;
    if (g < G_NUM) {
        float cnt  = gstat[2 * G_NUM + g];
        float norm = fmaxf(cnt * (float)H, 1.0f);
        float mean = gstat[g] / norm;
        float var  = gstat[G_NUM + g] / norm - mean * mean;
        gstat[3 * G_NUM + g] = mean;
        gstat[4 * G_NUM + g] = rsqrtf(var + LN_EPS);
    }
}

// ---------------------------------------------------------------------------
__global__ __launch_bounds__(256) void final_ln_kernel(
    float* __restrict__ h3, const int* __restrict__ batch,
    const float* __restrict__ lnw, const float* __restrict__ lnb,
    const float* __restrict__ gstat)
{
    int idx4 = blockIdx.x * 256 + threadIdx.x;
    if (idx4 >= N_NODES * 32) return;
    int node = idx4 >> 5;
    int c4 = (idx4 & 31) * 4;
    int g = batch[node];
    float mean = gstat[3 * G_NUM + g];
    float inv  = gstat[4 * G_NUM + g];
    float4 v = ((const float4*)h3)[idx4];
    float4 w = *(const float4*)&lnw[c4];
    float4 b = *(const float4*)&lnb[c4];
    v.x = fmaxf(0.f, (v.x - mean) * inv * w.x + b.x);
    v.y = fmaxf(0.f, (v.y - mean) * inv * w.y + b.y);
    v.z = fmaxf(0.f, (v.z - mean) * inv * w.z + b.z);
    v.w = fmaxf(0.f, (v.w - mean) * inv * w.w + b.w);
    ((float4*)h3)[idx4] = v;
}

// ---------------------------------------------------------------------------
extern "C" void kernel_launch(void* const* d_in, const int* in_sizes, int n_in,
                              void* d_out, int out_size, void* d_ws, size_t ws_size,
                              hipStream_t stream)
{
    const float* node  = (const float*)d_in[0];
    const int*   ei    = (const int*)d_in[1];
    // d_in[2] = edge_attr (unused)
    const int*   batch = (const int*)d_in[3];
    const float* epsp  = (const float*)d_in[4];
    const float* W1    = (const float*)d_in[5];
    const float* b1    = (const float*)d_in[6];
    const float* g1    = (const float*)d_in[7];
    const float* be1   = (const float*)d_in[8];
    const float* W2    = (const float*)d_in[9];
    const float* b2    = (const float*)d_in[10];
    const float* g2    = (const float*)d_in[11];
    const float* be2   = (const float*)d_in[12];
    const float* W3    = (const float*)d_in[13];
    const float* b3    = (const float*)d_in[14];
    const float* lnw   = (const float*)d_in[15];
    const float* lnb   = (const float*)d_in[16];

    float* out = (float*)d_out;

    // ws layout: gstat(512f) | deg(N) | off(N+1) | cursor(N) | csr(E) |
    //            blksum(98) | pad | WT(3*16384 bf16)          ~3.7 MB total
    float* gstat  = (float*)d_ws;
    int*   deg    = (int*)d_ws + 512;
    int*   off    = deg + N_NODES;
    int*   cursor = off + N_NODES + 1;
    int*   csr    = cursor + N_NODES;
    int*   blksum = csr + N_EDGES;
    unsigned short* WT = (unsigned short*)((int*)d_ws + 900612);  // 16B-aligned

    hipMemsetAsync(gstat, 0, 5 * G_NUM * sizeof(float), stream);
    hipMemsetAsync(deg, 0, N_NODES * sizeof(int), stream);

    // CSR build (by dst)
    hist_kernel<<<(N_EDGES + 255) / 256, 256, 0, stream>>>(ei, deg);
    scan1_kernel<<<SCAN_NB, 256, 0, stream>>>(deg, off, blksum);
    scan2_kernel<<<1, 128, 0, stream>>>(blksum);
    scan3_kernel<<<(N_NODES + 255) / 256, 256, 0, stream>>>(off, blksum, cursor);
    fill_kernel<<<(N_EDGES + 255) / 256, 256, 0, stream>>>(ei, cursor, csr);

    // bf16 transposed weights
    wt_prep_kernel<<<(3 * 16384 + 255) / 256, 256, 0, stream>>>(W1, W2, W3, WT);

    // fused gather + 3-layer MFMA MLP
    fused_mlp_kernel<<<(N_NODES + 63) / 64, 256, 0, stream>>>(
        node, off, csr, epsp, WT, b1, g1, be1, b2, g2, be2, b3, batch,
        out, gstat);

    finalize_stats_kernel<<<1, 64, 0, stream>>>(gstat);

    final_ln_kernel<<<(N_NODES * 32 + 255) / 256, 256, 0, stream>>>(
        out, batch, lnw, lnb, gstat);
}

// Round 5
// 353.779 us; speedup vs baseline: 3.9198x; 1.2401x over previous
//
#include <hip/hip_runtime.h>

#define N_NODES 100000
#define N_EDGES 600000
#define H 128
#define G_NUM 64
#define LN_EPS 1e-5f

// LDS bf16 row stride (conflict-free b128 frag reads)
#define WSTR 136

#define NTILES ((N_NODES + 63) / 64)     // 1563

#define SCAN_CHUNK 1024
#define SCAN_NB ((N_NODES + SCAN_CHUNK - 1) / SCAN_CHUNK)   // 98
#define FILL_NB ((N_EDGES + 255) / 256)                      // 2344
#define WT_NB ((3 * 16384 + 255) / 256)                      // 192

#define SCRATCH_PW 1088   // ints per wave of csr scratch (hB reuse: 4352 ints/4)

typedef __attribute__((ext_vector_type(8))) short short8;
typedef __attribute__((ext_vector_type(4))) float floatx4;

__device__ __forceinline__ unsigned short f2bf(float x) {
    unsigned int u = __float_as_uint(x);
    u += 0x7fffu + ((u >> 16) & 1u);
    return (unsigned short)(u >> 16);
}
__device__ __forceinline__ float bf2f(unsigned short h) {
    return __uint_as_float(((unsigned int)h) << 16);
}

// ---------------------------------------------------------------------------
// CSR build
// ---------------------------------------------------------------------------
__global__ __launch_bounds__(256) void hist_kernel(
    const int* __restrict__ ei, int* __restrict__ deg)
{
    int e = blockIdx.x * 256 + threadIdx.x;
    if (e >= N_EDGES) return;
    atomicAdd(&deg[ei[N_EDGES + e]], 1);
}

__global__ __launch_bounds__(256) void scan1_kernel(
    const int* __restrict__ deg, int* __restrict__ off,
    int* __restrict__ blksum)
{
    __shared__ int sA[256], sB[256];
    const int tid = threadIdx.x;
    const int base = blockIdx.x * SCAN_CHUNK + tid * 4;
    int v[4];
#pragma unroll
    for (int j = 0; j < 4; ++j) {
        int i = base + j;
        v[j] = (i < N_NODES) ? deg[i] : 0;
    }
    int tsum = v[0] + v[1] + v[2] + v[3];
    int* a = sA; int* b = sB;
    a[tid] = tsum;
    __syncthreads();
#pragma unroll
    for (int o = 1; o < 256; o <<= 1) {
        int t = a[tid] + ((tid >= o) ? a[tid - o] : 0);
        b[tid] = t;
        __syncthreads();
        int* tmp = a; a = b; b = tmp;
    }
    int run = a[tid] - tsum;
#pragma unroll
    for (int j = 0; j < 4; ++j) {
        int i = base + j;
        if (i < N_NODES) off[i] = run;
        run += v[j];
    }
    if (tid == 255) blksum[blockIdx.x] = a[255];
}

// scan2+scan3 fused; UNIFORM control flow around every __syncthreads.
__global__ __launch_bounds__(256) void scan23_kernel(
    int* __restrict__ off, const int* __restrict__ blksum,
    int* __restrict__ cursor)
{
    __shared__ int sA[128], sB[128];
    const int tid = threadIdx.x;
    if (tid < 128) sA[tid] = (tid < SCAN_NB) ? blksum[tid] : 0;
    __syncthreads();
    int* a = sA; int* b = sB;
#pragma unroll
    for (int o = 1; o < 128; o <<= 1) {
        int t = 0;
        if (tid < 128) t = a[tid] + ((tid >= o) ? a[tid - o] : 0);
        __syncthreads();
        if (tid < 128) b[tid] = t;
        __syncthreads();
        int* tmp = a; a = b; b = tmp;
    }
    // make exclusive, result guaranteed in sA
    int excl = 0;
    if (tid < 128) excl = a[tid] - ((tid < SCAN_NB) ? blksum[tid] : 0);
    __syncthreads();
    if (tid < 128) sA[tid] = excl;
    __syncthreads();

    int i = blockIdx.x * 256 + tid;
    if (i < N_NODES) {
        int val = off[i] + sA[i >> 10];
        off[i] = val;
        cursor[i] = val;
    }
    if (i == 0) off[N_NODES] = N_EDGES;
}

// fill + bf16-transposed-weight prep in one dispatch (disjoint block ranges)
__global__ __launch_bounds__(256) void fill_wt_kernel(
    const int* __restrict__ ei, int* __restrict__ cursor,
    int* __restrict__ csr,
    const float* __restrict__ W1, const float* __restrict__ W2,
    const float* __restrict__ W3, unsigned short* __restrict__ WT)
{
    int gb = blockIdx.x;
    if (gb < FILL_NB) {
        int e = gb * 256 + threadIdx.x;
        if (e >= N_EDGES) return;
        int dst = ei[N_EDGES + e];
        int pos = atomicAdd(&cursor[dst], 1);
        csr[pos] = ei[e];
    } else {
        int idx = (gb - FILL_NB) * 256 + threadIdx.x;
        if (idx >= 3 * 16384) return;
        int l = idx >> 14, r = idx & 16383;
        int k = r >> 7, n = r & 127;
        const float* W = (l == 0) ? W1 : ((l == 1) ? W2 : W3);
        WT[l * 16384 + n * 128 + k] = f2bf(W[k * 128 + n]);
    }
}

// ---------------------------------------------------------------------------
// MFMA helpers
// ---------------------------------------------------------------------------
__device__ __forceinline__ void stageWb(unsigned short* __restrict__ Wb,
                                        const unsigned short* __restrict__ WT,
                                        int tid)
{
#pragma unroll
    for (int t = 0; t < 8; ++t) {
        int c = tid + t * 256;
        int row = c >> 4, c8 = c & 15;
        *(short8*)&Wb[row * WSTR + c8 * 8] = *(const short8*)&WT[row * 128 + c8 * 8];
    }
}

__device__ __forceinline__ void gemm_frags(const unsigned short* __restrict__ hIn,
                                           const unsigned short* __restrict__ Wb,
                                           floatx4 acc[8], int w, int lane)
{
    const int c = lane & 15, q = lane >> 4;
#pragma unroll
    for (int nt = 0; nt < 8; ++nt) acc[nt] = (floatx4){0.f, 0.f, 0.f, 0.f};
#pragma unroll
    for (int kt = 0; kt < 4; ++kt) {
        short8 a = *(const short8*)&hIn[(w * 16 + c) * WSTR + kt * 32 + q * 8];
#pragma unroll
        for (int nt = 0; nt < 8; ++nt) {
            short8 b = *(const short8*)&Wb[(nt * 16 + c) * WSTR + kt * 32 + q * 8];
            acc[nt] = __builtin_amdgcn_mfma_f32_16x16x32_bf16(a, b, acc[nt], 0, 0, 0);
        }
    }
}

__device__ __forceinline__ void gemm_layer(const unsigned short* __restrict__ hIn,
                                           unsigned short* __restrict__ hOut,
                                           const unsigned short* __restrict__ Wb,
                                           const float* __restrict__ bias,
                                           int w, int lane)
{
    const int c = lane & 15, q = lane >> 4;
    floatx4 acc[8];
    gemm_frags(hIn, Wb, acc, w, lane);
#pragma unroll
    for (int nt = 0; nt < 8; ++nt) {
        float bv = bias[nt * 16 + c];
#pragma unroll
        for (int i = 0; i < 4; ++i)
            hOut[(w * 16 + q * 4 + i) * WSTR + nt * 16 + c] = f2bf(acc[nt][i] + bv);
    }
}

__device__ __forceinline__ void ln_pass(unsigned short* __restrict__ buf,
                                        const float* __restrict__ g,
                                        const float* __restrict__ be, int tid)
{
    const int row = tid >> 2, qt = tid & 3;
    unsigned short* rb = buf + row * WSTR + qt * 32;
    float v[32];
    float sum = 0.f, sq = 0.f;
#pragma unroll
    for (int j = 0; j < 4; ++j) {
        short8 t = *(const short8*)&rb[j * 8];
#pragma unroll
        for (int e = 0; e < 8; ++e) {
            float f = bf2f((unsigned short)t[e]);
            v[j * 8 + e] = f; sum += f; sq += f * f;
        }
    }
    sum += __shfl_xor(sum, 1); sum += __shfl_xor(sum, 2);
    sq  += __shfl_xor(sq, 1);  sq  += __shfl_xor(sq, 2);
    const float mu   = sum * (1.0f / 128.0f);
    const float rstd = rsqrtf(sq * (1.0f / 128.0f) - mu * mu + LN_EPS);
#pragma unroll
    for (int j = 0; j < 4; ++j) {
        const float4 g0 = *(const float4*)&g[qt * 32 + j * 8];
        const float4 g1 = *(const float4*)&g[qt * 32 + j * 8 + 4];
        const float4 e0 = *(const float4*)&be[qt * 32 + j * 8];
        const float4 e1 = *(const float4*)&be[qt * 32 + j * 8 + 4];
        const float gw[8] = {g0.x, g0.y, g0.z, g0.w, g1.x, g1.y, g1.z, g1.w};
        const float bw[8] = {e0.x, e0.y, e0.z, e0.w, e1.x, e1.y, e1.z, e1.w};
        short8 o;
#pragma unroll
        for (int e = 0; e < 8; ++e) {
            float val = fmaxf(0.f, (v[j * 8 + e] - mu) * rstd * gw[e] + bw[e]);
            o[e] = (short)f2bf(val);
        }
        *(short8*)&rb[j * 8] = o;
    }
}

// ---------------------------------------------------------------------------
// Fused kernel (one 64-row tile per block, NON-persistent):
// pipelined gather -> bf16 h0 -> 3x MFMA GEMM (+LN x2) -> fp32 out + stats
// ---------------------------------------------------------------------------
__global__ __launch_bounds__(256) void fused_mlp_kernel(
    const float* __restrict__ node, const int* __restrict__ off,
    const int* __restrict__ csr, const float* __restrict__ epsp,
    const unsigned short* __restrict__ WT,
    const float* __restrict__ b1, const float* __restrict__ g1,
    const float* __restrict__ be1,
    const float* __restrict__ b2, const float* __restrict__ g2,
    const float* __restrict__ be2,
    const float* __restrict__ b3, const int* __restrict__ batch,
    float* __restrict__ out, float* __restrict__ gstat)
{
    __shared__ unsigned short Wb[128 * WSTR];   // 34.8 KB
    __shared__ unsigned short hA[64 * WSTR];    // 17.4 KB
    __shared__ unsigned short hB[64 * WSTR];    // 17.4 KB (gather csr scratch too)
    __shared__ float prm[7 * 128];
    __shared__ float s_gsum[G_NUM], s_gsq[G_NUM], s_gcnt[G_NUM];

    const int tid = threadIdx.x;
    const int w = tid >> 6, lane = tid & 63;
    const int row0 = blockIdx.x * 64;

    if (tid < G_NUM) { s_gsum[tid] = 0.f; s_gsq[tid] = 0.f; s_gcnt[tid] = 0.f; }
    {
        const float* srcs[7] = {b1, g1, be1, b2, g2, be2, b3};
#pragma unroll
        for (int t = 0; t < 4; ++t) {
            int i = tid + t * 256;
            if (i < 7 * 128) prm[i] = srcs[i >> 7][i & 127];
        }
    }
    stageWb(Wb, WT, tid);                // W1

    // ---- pipelined gather: h0 = (1+eps)*x + sum neighbors -> hA (bf16)
    {
        const float2* np2 = (const float2*)node;
        const float epsv = 1.0f + epsp[0];
        const int n0 = row0 + w * 16;
        int oidx = n0 + ((lane < 17) ? lane : 16);
        if (oidx > N_NODES) oidx = N_NODES;
        const int offl = off[oidx];
        const int e_begin = __shfl(offl, 0);
        const int e_end   = __shfl(offl, 16);
        const int cnt = e_end - e_begin;

        float2 acc[16];
#pragma unroll
        for (int i = 0; i < 16; ++i) {
            int n = n0 + i;
            if (n < N_NODES) {
                float2 own = np2[(size_t)n * 64 + lane];
                acc[i].x = epsv * own.x; acc[i].y = epsv * own.y;
            } else {
                acc[i].x = 0.f; acc[i].y = 0.f;
            }
        }

        if (cnt <= SCRATCH_PW) {
            int* scr = ((int*)hB) + w * SCRATCH_PW;
            for (int k = lane; k < cnt; k += 64) scr[k] = csr[e_begin + k];
            __threadfence_block();       // drain ds_writes before same-wave reads

#pragma unroll
            for (int g4 = 0; g4 < 4; ++g4) {
                int p[4], e[4];
#pragma unroll
                for (int j = 0; j < 4; ++j) {
                    p[j] = __shfl(offl, g4 * 4 + j) - e_begin;
                    e[j] = __shfl(offl, g4 * 4 + j + 1) - e_begin;
                }
                float2 vc[4]; bool ac[4];
#pragma unroll
                for (int j = 0; j < 4; ++j) {
                    ac[j] = p[j] < e[j];
                    vc[j] = make_float2(0.f, 0.f);
                    if (ac[j]) {
                        int s = scr[p[j]];
                        vc[j] = np2[(size_t)s * 64 + lane];
                    }
                }
                while (ac[0] || ac[1] || ac[2] || ac[3]) {
                    float2 vn[4]; bool an[4];
#pragma unroll
                    for (int j = 0; j < 4; ++j) {   // prefetch next round
                        an[j] = (p[j] + 1) < e[j];
                        vn[j] = make_float2(0.f, 0.f);
                        if (an[j]) {
                            int s = scr[p[j] + 1];
                            vn[j] = np2[(size_t)s * 64 + lane];
                        }
                    }
#pragma unroll
                    for (int j = 0; j < 4; ++j) {   // consume current
                        if (ac[j]) {
                            acc[g4 * 4 + j].x += vc[j].x;
                            acc[g4 * 4 + j].y += vc[j].y;
                            p[j] += 1;
                        }
                        ac[j] = an[j];
                        vc[j] = vn[j];
                    }
                }
            }
        } else {
            // pathological-degree fallback (rare)
            for (int i = 0; i < 16; ++i) {
                int n = n0 + i;
                if (n >= N_NODES) continue;
                for (int j = off[n]; j < off[n + 1]; ++j) {
                    float2 v = np2[(size_t)csr[j] * 64 + lane];
                    acc[i].x += v.x; acc[i].y += v.y;
                }
            }
        }
#pragma unroll
        for (int i = 0; i < 16; ++i) {
            unsigned int pack = (unsigned)f2bf(acc[i].x) |
                                ((unsigned)f2bf(acc[i].y) << 16);
            ((unsigned int*)&hA[(w * 16 + i) * WSTR])[lane] = pack;
        }
    }
    __syncthreads();                     // hA + Wb(W1) + prm ready

    gemm_layer(hA, hB, Wb, &prm[0], w, lane);
    ln_pass(hB, &prm[128], &prm[256], tid);
    __syncthreads();
    stageWb(Wb, WT + 16384, tid);
    __syncthreads();

    gemm_layer(hB, hA, Wb, &prm[384], w, lane);
    ln_pass(hA, &prm[512], &prm[640], tid);
    __syncthreads();
    stageWb(Wb, WT + 32768, tid);
    __syncthreads();

    // layer 3 -> global + stats
    {
        const int c = lane & 15, q = lane >> 4;
        floatx4 acc3[8];
        gemm_frags(hA, Wb, acc3, w, lane);
        float sum[4] = {0.f, 0.f, 0.f, 0.f};
        float sq[4]  = {0.f, 0.f, 0.f, 0.f};
#pragma unroll
        for (int nt = 0; nt < 8; ++nt) {
            float bv = prm[768 + nt * 16 + c];
#pragma unroll
            for (int i = 0; i < 4; ++i) {
                float vv = acc3[nt][i] + bv;
                size_t nrow = (size_t)row0 + w * 16 + q * 4 + i;
                if (nrow < N_NODES)
                    out[nrow * H + nt * 16 + c] = vv;
                sum[i] += vv; sq[i] += vv * vv;
            }
        }
#pragma unroll
        for (int m = 1; m < 16; m <<= 1) {
#pragma unroll
            for (int i = 0; i < 4; ++i) {
                sum[i] += __shfl_xor(sum[i], m);
                sq[i]  += __shfl_xor(sq[i], m);
            }
        }
        if (c == 0) {
#pragma unroll
            for (int i = 0; i < 4; ++i) {
                size_t nrow = (size_t)row0 + w * 16 + q * 4 + i;
                if (nrow < N_NODES) {
                    int g = batch[nrow];
                    atomicAdd(&s_gsum[g], sum[i]);
                    atomicAdd(&s_gsq[g], sq[i]);
                    atomicAdd(&s_gcnt[g], 1.0f);
                }
            }
        }
    }
    __syncthreads();
    if (tid < G_NUM && s_gcnt[tid] > 0.f) {
        unsafeAtomicAdd(&gstat[tid], s_gsum[tid]);
        unsafeAtomicAdd(&gstat[G_NUM + tid], s_gsq[tid]);
        unsafeAtomicAdd(&gstat[2 * G_NUM + tid], s_gcnt[tid]);
    }
}

// ---------------------------------------------------------------------------
__global__ void finalize_stats_kernel(float* __restrict__ gstat)
{
    int g = threadIdx.x;
    if (g < G_NUM) {
        float cnt  = gstat[2 * G_NUM + g];
        float norm = fmaxf(cnt * (float)H, 1.0f);
        float mean = gstat[g] / norm;
        float var  = gstat[G_NUM + g] / norm - mean * mean;
        gstat[3 * G_NUM + g] = mean;
        gstat[4 * G_NUM + g] = rsqrtf(var + LN_EPS);
    }
}

// ---------------------------------------------------------------------------
__global__ __launch_bounds__(256) void final_ln_kernel(
    float* __restrict__ h3, const int* __restrict__ batch,
    const float* __restrict__ lnw, const float* __restrict__ lnb,
    const float* __restrict__ gstat)
{
    int idx4 = blockIdx.x * 256 + threadIdx.x;
    if (idx4 >= N_NODES * 32) return;
    int node = idx4 >> 5;
    int c4 = (idx4 & 31) * 4;
    int g = batch[node];
    float mean = gstat[3 * G_NUM + g];
    float inv  = gstat[4 * G_NUM + g];
    float4 v = ((const float4*)h3)[idx4];
    float4 w = *(const float4*)&lnw[c4];
    float4 b = *(const float4*)&lnb[c4];
    v.x = fmaxf(0.f, (v.x - mean) * inv * w.x + b.x);
    v.y = fmaxf(0.f, (v.y - mean) * inv * w.y + b.y);
    v.z = fmaxf(0.f, (v.z - mean) * inv * w.z + b.z);
    v.w = fmaxf(0.f, (v.w - mean) * inv * w.w + b.w);
    ((float4*)h3)[idx4] = v;
}

// ---------------------------------------------------------------------------
extern "C" void kernel_launch(void* const* d_in, const int* in_sizes, int n_in,
                              void* d_out, int out_size, void* d_ws, size_t ws_size,
                              hipStream_t stream)
{
    const float* node  = (const float*)d_in[0];
    const int*   ei    = (const int*)d_in[1];
    // d_in[2] = edge_attr (unused)
    const int*   batch = (const int*)d_in[3];
    const float* epsp  = (const float*)d_in[4];
    const float* W1    = (const float*)d_in[5];
    const float* b1    = (const float*)d_in[6];
    const float* g1    = (const float*)d_in[7];
    const float* be1   = (const float*)d_in[8];
    const float* W2    = (const float*)d_in[9];
    const float* b2    = (const float*)d_in[10];
    const float* g2    = (const float*)d_in[11];
    const float* be2   = (const float*)d_in[12];
    const float* W3    = (const float*)d_in[13];
    const float* b3    = (const float*)d_in[14];
    const float* lnw   = (const float*)d_in[15];
    const float* lnb   = (const float*)d_in[16];

    float* out = (float*)d_out;

    // ws layout: gstat(512f) | deg(N) | off(N+1) | cursor(N) | csr(E) |
    //            blksum | pad | WT(3*16k bf16)
    float* gstat  = (float*)d_ws;
    int*   deg    = (int*)d_ws + 512;
    int*   off    = deg + N_NODES;
    int*   cursor = off + N_NODES + 1;
    int*   csr    = cursor + N_NODES;
    int*   blksum = csr + N_EDGES;
    unsigned short* WT = (unsigned short*)((int*)d_ws + 900612);  // 16B-aligned

    // single memset covers gstat (512 floats) + adjacent deg (N ints)
    hipMemsetAsync(d_ws, 0, (512 + N_NODES) * sizeof(int), stream);

    hist_kernel<<<(N_EDGES + 255) / 256, 256, 0, stream>>>(ei, deg);
    scan1_kernel<<<SCAN_NB, 256, 0, stream>>>(deg, off, blksum);
    scan23_kernel<<<(N_NODES + 255) / 256, 256, 0, stream>>>(off, blksum, cursor);
    fill_wt_kernel<<<FILL_NB + WT_NB, 256, 0, stream>>>(ei, cursor, csr,
                                                        W1, W2, W3, WT);

    fused_mlp_kernel<<<NTILES, 256, 0, stream>>>(
        node, off, csr, epsp, WT, b1, g1, be1, b2, g2, be2, b3, batch,
        out, gstat);

    finalize_stats_kernel<<<1, 64, 0, stream>>>(gstat);

    final_ln_kernel<<<(N_NODES * 32 + 255) / 256, 256, 0, stream>>>(
        out, batch, lnw, lnb, gstat);
}

// Round 6
// 345.941 us; speedup vs baseline: 4.0086x; 1.0227x over previous
//
#include <hip/hip_runtime.h>

#define N_NODES 100000
#define N_EDGES 600000
#define H 128
#define G_NUM 64
#define LN_EPS 1e-5f

// LDS bf16 row stride (conflict-free b128 frag reads)
#define WSTR 136

#define NTILES ((N_NODES + 63) / 64)     // 1563

#define SCAN_CHUNK 1024
#define SCAN_NB ((N_NODES + SCAN_CHUNK - 1) / SCAN_CHUNK)   // 98
#define FILL_NB ((N_EDGES + 255) / 256)                      // 2344
#define WT_NB ((3 * 16384 + 255) / 256)                      // 192

#define SCRATCH_PW 1088   // ints per wave of csr scratch (hB reuse: 4352 ints/4)

typedef __attribute__((ext_vector_type(8))) short short8;
typedef __attribute__((ext_vector_type(4))) float floatx4;

__device__ __forceinline__ unsigned short f2bf(float x) {
    unsigned int u = __float_as_uint(x);
    u += 0x7fffu + ((u >> 16) & 1u);
    return (unsigned short)(u >> 16);
}

// ---------------------------------------------------------------------------
// CSR build
// ---------------------------------------------------------------------------
__global__ __launch_bounds__(256) void hist_kernel(
    const int* __restrict__ ei, int* __restrict__ deg)
{
    int e = blockIdx.x * 256 + threadIdx.x;
    if (e >= N_EDGES) return;
    atomicAdd(&deg[ei[N_EDGES + e]], 1);
}

__global__ __launch_bounds__(256) void scan1_kernel(
    const int* __restrict__ deg, int* __restrict__ off,
    int* __restrict__ blksum)
{
    __shared__ int sA[256], sB[256];
    const int tid = threadIdx.x;
    const int base = blockIdx.x * SCAN_CHUNK + tid * 4;
    int v[4];
#pragma unroll
    for (int j = 0; j < 4; ++j) {
        int i = base + j;
        v[j] = (i < N_NODES) ? deg[i] : 0;
    }
    int tsum = v[0] + v[1] + v[2] + v[3];
    int* a = sA; int* b = sB;
    a[tid] = tsum;
    __syncthreads();
#pragma unroll
    for (int o = 1; o < 256; o <<= 1) {
        int t = a[tid] + ((tid >= o) ? a[tid - o] : 0);
        b[tid] = t;
        __syncthreads();
        int* tmp = a; a = b; b = tmp;
    }
    int run = a[tid] - tsum;
#pragma unroll
    for (int j = 0; j < 4; ++j) {
        int i = base + j;
        if (i < N_NODES) off[i] = run;
        run += v[j];
    }
    if (tid == 255) blksum[blockIdx.x] = a[255];
}

// scan2+scan3 fused; UNIFORM control flow around every __syncthreads.
__global__ __launch_bounds__(256) void scan23_kernel(
    int* __restrict__ off, const int* __restrict__ blksum,
    int* __restrict__ cursor)
{
    __shared__ int sA[128], sB[128];
    const int tid = threadIdx.x;
    if (tid < 128) sA[tid] = (tid < SCAN_NB) ? blksum[tid] : 0;
    __syncthreads();
    int* a = sA; int* b = sB;
#pragma unroll
    for (int o = 1; o < 128; o <<= 1) {
        int t = 0;
        if (tid < 128) t = a[tid] + ((tid >= o) ? a[tid - o] : 0);
        __syncthreads();
        if (tid < 128) b[tid] = t;
        __syncthreads();
        int* tmp = a; a = b; b = tmp;
    }
    int excl = 0;
    if (tid < 128) excl = a[tid] - ((tid < SCAN_NB) ? blksum[tid] : 0);
    __syncthreads();
    if (tid < 128) sA[tid] = excl;
    __syncthreads();

    int i = blockIdx.x * 256 + tid;
    if (i < N_NODES) {
        int val = off[i] + sA[i >> 10];
        off[i] = val;
        cursor[i] = val;
    }
    if (i == 0) off[N_NODES] = N_EDGES;
}

// fill + bf16-transposed-weight prep in one dispatch (disjoint block ranges)
__global__ __launch_bounds__(256) void fill_wt_kernel(
    const int* __restrict__ ei, int* __restrict__ cursor,
    int* __restrict__ csr,
    const float* __restrict__ W1, const float* __restrict__ W2,
    const float* __restrict__ W3, unsigned short* __restrict__ WT)
{
    int gb = blockIdx.x;
    if (gb < FILL_NB) {
        int e = gb * 256 + threadIdx.x;
        if (e >= N_EDGES) return;
        int dst = ei[N_EDGES + e];
        int pos = atomicAdd(&cursor[dst], 1);
        csr[pos] = ei[e];
    } else {
        int idx = (gb - FILL_NB) * 256 + threadIdx.x;
        if (idx >= 3 * 16384) return;
        int l = idx >> 14, r = idx & 16383;
        int k = r >> 7, n = r & 127;
        const float* W = (l == 0) ? W1 : ((l == 1) ? W2 : W3);
        WT[l * 16384 + n * 128 + k] = f2bf(W[k * 128 + n]);
    }
}

// ---------------------------------------------------------------------------
// MFMA helpers — B-fragments straight from global WT (L1/L2-resident, shared
// by every wave on the device; no LDS staging, no barriers needed).
// ---------------------------------------------------------------------------
__device__ __forceinline__ void gemm_frags(const unsigned short* __restrict__ hIn,
                                           const unsigned short* __restrict__ WTl,
                                           floatx4 acc[8], int w, int lane)
{
    const int c = lane & 15, q = lane >> 4;
#pragma unroll
    for (int nt = 0; nt < 8; ++nt) acc[nt] = (floatx4){0.f, 0.f, 0.f, 0.f};
#pragma unroll
    for (int kt = 0; kt < 4; ++kt) {
        short8 a = *(const short8*)&hIn[(w * 16 + c) * WSTR + kt * 32 + q * 8];
#pragma unroll
        for (int nt = 0; nt < 8; ++nt) {
            short8 b = *(const short8*)&WTl[(nt * 16 + c) * 128 + kt * 32 + q * 8];
            acc[nt] = __builtin_amdgcn_mfma_f32_16x16x32_bf16(a, b, acc[nt], 0, 0, 0);
        }
    }
}

// GEMM + bias + per-row LayerNorm + ReLU fused in registers -> bf16 to LDS.
// Row r = w*16+q*4+i lives across the 16 c-lanes (8 nt cols each) -> row
// stats via 16-lane shuffle reduce; no LDS round-trip for LN.
__device__ __forceinline__ void gemm_layer_ln(const unsigned short* __restrict__ hIn,
                                              unsigned short* __restrict__ hOut,
                                              const unsigned short* __restrict__ WTl,
                                              const float* __restrict__ bias,
                                              const float* __restrict__ g,
                                              const float* __restrict__ be,
                                              int w, int lane)
{
    const int c = lane & 15, q = lane >> 4;
    floatx4 acc[8];
    gemm_frags(hIn, WTl, acc, w, lane);

    float sum[4] = {0.f, 0.f, 0.f, 0.f};
    float sq[4]  = {0.f, 0.f, 0.f, 0.f};
#pragma unroll
    for (int nt = 0; nt < 8; ++nt) {
        float bv = bias[nt * 16 + c];
#pragma unroll
        for (int i = 0; i < 4; ++i) {
            float vv = acc[nt][i] + bv;
            acc[nt][i] = vv;
            sum[i] += vv; sq[i] += vv * vv;
        }
    }
#pragma unroll
    for (int m = 1; m < 16; m <<= 1) {
#pragma unroll
        for (int i = 0; i < 4; ++i) {
            sum[i] += __shfl_xor(sum[i], m);
            sq[i]  += __shfl_xor(sq[i], m);
        }
    }
    float mu[4], rstd[4];
#pragma unroll
    for (int i = 0; i < 4; ++i) {
        mu[i]   = sum[i] * (1.0f / 128.0f);
        rstd[i] = rsqrtf(sq[i] * (1.0f / 128.0f) - mu[i] * mu[i] + LN_EPS);
    }
#pragma unroll
    for (int nt = 0; nt < 8; ++nt) {
        float gw = g[nt * 16 + c];
        float bw = be[nt * 16 + c];
#pragma unroll
        for (int i = 0; i < 4; ++i) {
            float val = fmaxf(0.f, (acc[nt][i] - mu[i]) * rstd[i] * gw + bw);
            hOut[(w * 16 + q * 4 + i) * WSTR + nt * 16 + c] = f2bf(val);
        }
    }
}

// ---------------------------------------------------------------------------
// Fused kernel (one 64-row tile per block, 4 blocks/CU):
// pipelined gather -> bf16 h0 -> 3x MFMA GEMM (LN fused) -> fp32 out + stats.
// Each wave's 16 rows are wave-private end-to-end: only 2 barriers total.
// ---------------------------------------------------------------------------
__global__ __launch_bounds__(256, 4) void fused_mlp_kernel(
    const float* __restrict__ node, const int* __restrict__ off,
    const int* __restrict__ csr, const float* __restrict__ epsp,
    const unsigned short* __restrict__ WT,
    const float* __restrict__ b1, const float* __restrict__ g1,
    const float* __restrict__ be1,
    const float* __restrict__ b2, const float* __restrict__ g2,
    const float* __restrict__ be2,
    const float* __restrict__ b3, const int* __restrict__ batch,
    float* __restrict__ out, float* __restrict__ gstat)
{
    __shared__ unsigned short hA[64 * WSTR];    // 17.4 KB
    __shared__ unsigned short hB[64 * WSTR];    // 17.4 KB (gather csr scratch too)
    __shared__ float prm[7 * 128];              // 3.6 KB
    __shared__ float s_gsum[G_NUM], s_gsq[G_NUM], s_gcnt[G_NUM];
    // total ~39.2 KB -> 4 blocks/CU

    const int tid = threadIdx.x;
    const int w = tid >> 6, lane = tid & 63;
    const int row0 = blockIdx.x * 64;

    if (tid < G_NUM) { s_gsum[tid] = 0.f; s_gsq[tid] = 0.f; s_gcnt[tid] = 0.f; }
    {
        const float* srcs[7] = {b1, g1, be1, b2, g2, be2, b3};
#pragma unroll
        for (int t = 0; t < 4; ++t) {
            int i = tid + t * 256;
            if (i < 7 * 128) prm[i] = srcs[i >> 7][i & 127];
        }
    }

    // ---- pipelined gather: h0 = (1+eps)*x + sum neighbors -> hA (bf16)
    {
        const float2* np2 = (const float2*)node;
        const float epsv = 1.0f + epsp[0];
        const int n0 = row0 + w * 16;
        int oidx = n0 + ((lane < 17) ? lane : 16);
        if (oidx > N_NODES) oidx = N_NODES;
        const int offl = off[oidx];
        const int e_begin = __shfl(offl, 0);
        const int e_end   = __shfl(offl, 16);
        const int cnt = e_end - e_begin;

        float2 acc[16];
#pragma unroll
        for (int i = 0; i < 16; ++i) {
            int n = n0 + i;
            if (n < N_NODES) {
                float2 own = np2[(size_t)n * 64 + lane];
                acc[i].x = epsv * own.x; acc[i].y = epsv * own.y;
            } else {
                acc[i].x = 0.f; acc[i].y = 0.f;
            }
        }

        if (cnt <= SCRATCH_PW) {
            int* scr = ((int*)hB) + w * SCRATCH_PW;
            for (int k = lane; k < cnt; k += 64) scr[k] = csr[e_begin + k];
            __threadfence_block();       // drain ds_writes before same-wave reads

#pragma unroll
            for (int g4 = 0; g4 < 4; ++g4) {
                int p[4], e[4];
#pragma unroll
                for (int j = 0; j < 4; ++j) {
                    p[j] = __shfl(offl, g4 * 4 + j) - e_begin;
                    e[j] = __shfl(offl, g4 * 4 + j + 1) - e_begin;
                }
                float2 vc[4]; bool ac[4];
#pragma unroll
                for (int j = 0; j < 4; ++j) {
                    ac[j] = p[j] < e[j];
                    vc[j] = make_float2(0.f, 0.f);
                    if (ac[j]) {
                        int s = scr[p[j]];
                        vc[j] = np2[(size_t)s * 64 + lane];
                    }
                }
                while (ac[0] || ac[1] || ac[2] || ac[3]) {
                    float2 vn[4]; bool an[4];
#pragma unroll
                    for (int j = 0; j < 4; ++j) {   // prefetch next round
                        an[j] = (p[j] + 1) < e[j];
                        vn[j] = make_float2(0.f, 0.f);
                        if (an[j]) {
                            int s = scr[p[j] + 1];
                            vn[j] = np2[(size_t)s * 64 + lane];
                        }
                    }
#pragma unroll
                    for (int j = 0; j < 4; ++j) {   // consume current
                        if (ac[j]) {
                            acc[g4 * 4 + j].x += vc[j].x;
                            acc[g4 * 4 + j].y += vc[j].y;
                            p[j] += 1;
                        }
                        ac[j] = an[j];
                        vc[j] = vn[j];
                    }
                }
            }
        } else {
            // pathological-degree fallback (rare)
            for (int i = 0; i < 16; ++i) {
                int n = n0 + i;
                if (n >= N_NODES) continue;
                for (int j = off[n]; j < off[n + 1]; ++j) {
                    float2 v = np2[(size_t)csr[j] * 64 + lane];
                    acc[i].x += v.x; acc[i].y += v.y;
                }
            }
        }
#pragma unroll
        for (int i = 0; i < 16; ++i) {
            unsigned int pack = (unsigned)f2bf(acc[i].x) |
                                ((unsigned)f2bf(acc[i].y) << 16);
            ((unsigned int*)&hA[(w * 16 + i) * WSTR])[lane] = pack;
        }
    }
    __syncthreads();   // prm visible (hA/hB are wave-private — barrier is for prm)

    gemm_layer_ln(hA, hB, WT,         &prm[0],   &prm[128], &prm[256], w, lane);
    gemm_layer_ln(hB, hA, WT + 16384, &prm[384], &prm[512], &prm[640], w, lane);

    // layer 3 -> global + stats
    {
        const int c = lane & 15, q = lane >> 4;
        floatx4 acc3[8];
        gemm_frags(hA, WT + 32768, acc3, w, lane);
        float sum[4] = {0.f, 0.f, 0.f, 0.f};
        float sq[4]  = {0.f, 0.f, 0.f, 0.f};
#pragma unroll
        for (int nt = 0; nt < 8; ++nt) {
            float bv = prm[768 + nt * 16 + c];
#pragma unroll
            for (int i = 0; i < 4; ++i) {
                float vv = acc3[nt][i] + bv;
                size_t nrow = (size_t)row0 + w * 16 + q * 4 + i;
                if (nrow < N_NODES)
                    out[nrow * H + nt * 16 + c] = vv;
                sum[i] += vv; sq[i] += vv * vv;
            }
        }
#pragma unroll
        for (int m = 1; m < 16; m <<= 1) {
#pragma unroll
            for (int i = 0; i < 4; ++i) {
                sum[i] += __shfl_xor(sum[i], m);
                sq[i]  += __shfl_xor(sq[i], m);
            }
        }
        if (c == 0) {
#pragma unroll
            for (int i = 0; i < 4; ++i) {
                size_t nrow = (size_t)row0 + w * 16 + q * 4 + i;
                if (nrow < N_NODES) {
                    int g = batch[nrow];
                    atomicAdd(&s_gsum[g], sum[i]);
                    atomicAdd(&s_gsq[g], sq[i]);
                    atomicAdd(&s_gcnt[g], 1.0f);
                }
            }
        }
    }
    __syncthreads();
    if (tid < G_NUM && s_gcnt[tid] > 0.f) {
        unsafeAtomicAdd(&gstat[tid], s_gsum[tid]);
        unsafeAtomicAdd(&gstat[G_NUM + tid], s_gsq[tid]);
        unsafeAtomicAdd(&gstat[2 * G_NUM + tid], s_gcnt[tid]);
    }
}

// ---------------------------------------------------------------------------
// Graph-LN apply + ReLU (finalize folded in: per-thread mean/inv from sums)
// ---------------------------------------------------------------------------
__global__ __launch_bounds__(256) void final_ln_kernel(
    float* __restrict__ h3, const int* __restrict__ batch,
    const float* __restrict__ lnw, const float* __restrict__ lnb,
    const float* __restrict__ gstat)
{
    int idx4 = blockIdx.x * 256 + threadIdx.x;
    if (idx4 >= N_NODES * 32) return;
    int node = idx4 >> 5;
    int c4 = (idx4 & 31) * 4;
    int g = batch[node];
    float s   = gstat[g];
    float qq  = gstat[G_NUM + g];
    float cnt = gstat[2 * G_NUM + g];
    float norm = fmaxf(cnt * (float)H, 1.0f);
    float mean = s / norm;
    float var  = qq / norm - mean * mean;
    float inv  = rsqrtf(var + LN_EPS);
    float4 v = ((const float4*)h3)[idx4];
    float4 w = *(const float4*)&lnw[c4];
    float4 b = *(const float4*)&lnb[c4];
    v.x = fmaxf(0.f, (v.x - mean) * inv * w.x + b.x);
    v.y = fmaxf(0.f, (v.y - mean) * inv * w.y + b.y);
    v.z = fmaxf(0.f, (v.z - mean) * inv * w.z + b.z);
    v.w = fmaxf(0.f, (v.w - mean) * inv * w.w + b.w);
    ((float4*)h3)[idx4] = v;
}

// ---------------------------------------------------------------------------
extern "C" void kernel_launch(void* const* d_in, const int* in_sizes, int n_in,
                              void* d_out, int out_size, void* d_ws, size_t ws_size,
                              hipStream_t stream)
{
    const float* node  = (const float*)d_in[0];
    const int*   ei    = (const int*)d_in[1];
    // d_in[2] = edge_attr (unused)
    const int*   batch = (const int*)d_in[3];
    const float* epsp  = (const float*)d_in[4];
    const float* W1    = (const float*)d_in[5];
    const float* b1    = (const float*)d_in[6];
    const float* g1    = (const float*)d_in[7];
    const float* be1   = (const float*)d_in[8];
    const float* W2    = (const float*)d_in[9];
    const float* b2    = (const float*)d_in[10];
    const float* g2    = (const float*)d_in[11];
    const float* be2   = (const float*)d_in[12];
    const float* W3    = (const float*)d_in[13];
    const float* b3    = (const float*)d_in[14];
    const float* lnw   = (const float*)d_in[15];
    const float* lnb   = (const float*)d_in[16];

    float* out = (float*)d_out;

    // ws layout: gstat(512f) | deg(N) | off(N+1) | cursor(N) | csr(E) |
    //            blksum | pad | WT(3*16k bf16)
    float* gstat  = (float*)d_ws;
    int*   deg    = (int*)d_ws + 512;
    int*   off    = deg + N_NODES;
    int*   cursor = off + N_NODES + 1;
    int*   csr    = cursor + N_NODES;
    int*   blksum = csr + N_EDGES;
    unsigned short* WT = (unsigned short*)((int*)d_ws + 900612);  // 16B-aligned

    // single memset covers gstat (512 floats) + adjacent deg (N ints)
    hipMemsetAsync(d_ws, 0, (512 + N_NODES) * sizeof(int), stream);

    hist_kernel<<<(N_EDGES + 255) / 256, 256, 0, stream>>>(ei, deg);
    scan1_kernel<<<SCAN_NB, 256, 0, stream>>>(deg, off, blksum);
    scan23_kernel<<<(N_NODES + 255) / 256, 256, 0, stream>>>(off, blksum, cursor);
    fill_wt_kernel<<<FILL_NB + WT_NB, 256, 0, stream>>>(ei, cursor, csr,
                                                        W1, W2, W3, WT);

    fused_mlp_kernel<<<NTILES, 256, 0, stream>>>(
        node, off, csr, epsp, WT, b1, g1, be1, b2, g2, be2, b3, batch,
        out, gstat);

    final_ln_kernel<<<(N_NODES * 32 + 255) / 256, 256, 0, stream>>>(
        out, batch, lnw, lnb, gstat);
}